// Round 7
// baseline (59.582 us; speedup 1.0000x reference)
//
#include <hip/hip_runtime.h>

// RoiAlign on FPN pyramid.  Output: (1, N, 14, 14, 256) fp32.  N = 512.
// R6: persistent work-balanced kernel. 1024 blocks x 4 waves, all resident
//     (launch_bounds(256,4) -> <=128 VGPR -> 4 blocks/CU). Each wave owns a
//     contiguous run of position-pairs (units); 2-deep software pipeline:
//     issue next pair's 8 float4 loads before consuming the current pair.
//     Box params cached per wave (uniform branch). XCD-chunked block swizzle
//     keeps each wave's boxes on one XCD's L2. Exact cover, no tail.

#define CROP 14
#define POS 196
#define HALF 98            // POS/2, positions come in pairs within a box
#define C 256
#define CANON 224.0f
#define EPSF 1e-7f
#define NBLK 1024

typedef float vfloat4 __attribute__((ext_vector_type(4)));

struct BoxState {
    int box;
    const float* f;
    int s;
    float fh, ny1, nx1, ny2, nx2;
};

struct PosP {
    float fx, fy;
    bool  v;
    const float *pTL, *pTR, *pBL, *pBR;
};

__device__ __forceinline__ void update_box(
    BoxState& bs, int box, const float* __restrict__ boxes,
    float imgh, float imgw,
    const float* f0, const float* f1, const float* f2,
    const float* f3, const float* f4)
{
    bs.box = box;
    const float bx1 = boxes[box * 4 + 0];
    const float by1 = boxes[box * 4 + 1];
    const float bx2 = boxes[box * 4 + 2];
    const float by2 = boxes[box * 4 + 3];
    const float w  = bx2 - bx1;
    const float h  = by2 - by1;
    const float sz = sqrtf(w * h);
    float lvf = floorf(1.0f + log2f(sz / CANON + EPSF));
    lvf = fminf(fmaxf(lvf, 0.0f), 4.0f);
    const int lv = (int)lvf;
    const int s  = 256 >> lv;
    const float fh = (float)s;
    bs.s = s; bs.fh = fh;
    bs.f = (lv == 0) ? f0 : (lv == 1) ? f1 : (lv == 2) ? f2 : (lv == 3) ? f3 : f4;
    bs.ny1 = by1 / imgh * fh / (fh - 1.0f);
    bs.nx1 = bx1 / imgw * fh / (fh - 1.0f);
    bs.ny2 = (by2 / imgh * fh - 1.0f) / (fh - 1.0f);
    bs.nx2 = (bx2 / imgw * fh - 1.0f) / (fh - 1.0f);
}

__device__ __forceinline__ PosP pos_params(const BoxState& bs, int p, int cbase)
{
    const int py = p / CROP;
    const int px = p % CROP;
    const float ty = (float)py / (float)(CROP - 1);
    const float tx = (float)px / (float)(CROP - 1);
    const float yc = (bs.ny1 * (1.0f - ty) + bs.ny2 * ty) * (bs.fh - 1.0f);
    const float xc = (bs.nx1 * (1.0f - tx) + bs.nx2 * tx) * (bs.fh - 1.0f);

    const float ylo = floorf(yc);
    const int y0  = (int)fminf(fmaxf(ylo,        0.0f), bs.fh - 1.0f);
    const int y1i = (int)fminf(fmaxf(ylo + 1.0f, 0.0f), bs.fh - 1.0f);
    const bool vy = (yc >= 0.0f) && (yc <= bs.fh - 1.0f);

    const float xlo = floorf(xc);
    const int x0  = (int)fminf(fmaxf(xlo,        0.0f), bs.fh - 1.0f);
    const int x1i = (int)fminf(fmaxf(xlo + 1.0f, 0.0f), bs.fh - 1.0f);
    const bool vx = (xc >= 0.0f) && (xc <= bs.fh - 1.0f);

    PosP r;
    r.fx = xc - xlo;
    r.fy = yc - ylo;
    r.v  = vy && vx;
    r.pTL = bs.f + ((size_t)y0  * bs.s + x0 ) * C + cbase;
    r.pTR = bs.f + ((size_t)y0  * bs.s + x1i) * C + cbase;
    r.pBL = bs.f + ((size_t)y1i * bs.s + x0 ) * C + cbase;
    r.pBR = bs.f + ((size_t)y1i * bs.s + x1i) * C + cbase;
    return r;
}

// issue loads for one pair (uniform valid-branch: skip loads if masked)
#define ISSUE(P0, P1, d0,d1,d2,d3,d4,d5,d6,d7)            \
    if (P0.v) { d0 = *(const vfloat4*)P0.pTL;             \
                d1 = *(const vfloat4*)P0.pTR;             \
                d2 = *(const vfloat4*)P0.pBL;             \
                d3 = *(const vfloat4*)P0.pBR; }           \
    if (P1.v) { d4 = *(const vfloat4*)P1.pTL;             \
                d5 = *(const vfloat4*)P1.pTR;             \
                d6 = *(const vfloat4*)P1.pBL;             \
                d7 = *(const vfloat4*)P1.pBR; }

#define CONSUME(P0, P1, oo, d0,d1,d2,d3,d4,d5,d6,d7)                         \
    {                                                                         \
        vfloat4 r0, r1;                                                       \
        if (P0.v) {                                                           \
            vfloat4 top = d0 + (d1 - d0) * P0.fx;                             \
            vfloat4 bot = d2 + (d3 - d2) * P0.fx;                             \
            r0 = top + (bot - top) * P0.fy;                                   \
        } else r0 = (vfloat4)0.0f;                                            \
        if (P1.v) {                                                           \
            vfloat4 top = d4 + (d5 - d4) * P1.fx;                             \
            vfloat4 bot = d6 + (d7 - d6) * P1.fx;                             \
            r1 = top + (bot - top) * P1.fy;                                   \
        } else r1 = (vfloat4)0.0f;                                            \
        __builtin_nontemporal_store(r0, (vfloat4*)(out + (oo)));              \
        __builtin_nontemporal_store(r1, (vfloat4*)(out + (oo) + C));          \
    }

__global__ __launch_bounds__(256, 4) void roi_align_persist(
    const int* __restrict__ image_shape,
    const float* __restrict__ boxes,
    const float* __restrict__ f0,
    const float* __restrict__ f1,
    const float* __restrict__ f2,
    const float* __restrict__ f3,
    const float* __restrict__ f4,
    float* __restrict__ out,
    int units, int nwaves)
{
    // XCD-chunk swizzle: blocks 0..NBLK-1, hw xcd = blk & 7.
    const int blk  = blockIdx.x;
    const int xcd  = blk & 7, slot = blk >> 3;
    const int sblk = xcd * (gridDim.x >> 3) + slot;
    const int wave = threadIdx.x >> 6;
    const int lane = threadIdx.x & 63;
    const int wgid = sblk * 4 + wave;

    const int K = units / nwaves, R = units % nwaves;
    const int start = wgid * K + (wgid < R ? wgid : R);
    const int cnt   = K + (wgid < R ? 1 : 0);
    if (cnt <= 0) return;

    const float imgh = (float)image_shape[1];
    const float imgw = (float)image_shape[2];
    const int cbase = lane * 4;

    BoxState bs; bs.box = -1;

    int u   = start;
    int end = start + cnt;

    // prologue: group A for unit u
    int boxA = u / HALF;
    if (boxA != bs.box) update_box(bs, boxA, boxes, imgh, imgw, f0, f1, f2, f3, f4);
    int ppA = (u - boxA * HALF) * 2;
    PosP a0 = pos_params(bs, ppA,     cbase);
    PosP a1 = pos_params(bs, ppA + 1, cbase);
    size_t ooA = (size_t)2 * (size_t)u * C + cbase;
    vfloat4 dA0, dA1, dA2, dA3, dA4, dA5, dA6, dA7;
    ISSUE(a0, a1, dA0, dA1, dA2, dA3, dA4, dA5, dA6, dA7);

    PosP b0, b1;
    size_t ooB = 0;
    vfloat4 dB0, dB1, dB2, dB3, dB4, dB5, dB6, dB7;

    for (;;) {
        // phase A: prefetch B (unit u+1), then consume A (unit u)
        const bool hasB = (u + 1 < end);
        if (hasB) {
            const int un = u + 1;
            const int boxB = un / HALF;
            if (boxB != bs.box) update_box(bs, boxB, boxes, imgh, imgw, f0, f1, f2, f3, f4);
            const int ppB = (un - boxB * HALF) * 2;
            b0 = pos_params(bs, ppB,     cbase);
            b1 = pos_params(bs, ppB + 1, cbase);
            ooB = (size_t)2 * (size_t)un * C + cbase;
            ISSUE(b0, b1, dB0, dB1, dB2, dB3, dB4, dB5, dB6, dB7);
        }
        CONSUME(a0, a1, ooA, dA0, dA1, dA2, dA3, dA4, dA5, dA6, dA7);
        ++u;
        if (!hasB) break;

        // phase B: prefetch A (unit u+1), then consume B (unit u)
        const bool hasA = (u + 1 < end);
        if (hasA) {
            const int un = u + 1;
            const int boxN = un / HALF;
            if (boxN != bs.box) update_box(bs, boxN, boxes, imgh, imgw, f0, f1, f2, f3, f4);
            const int ppN = (un - boxN * HALF) * 2;
            a0 = pos_params(bs, ppN,     cbase);
            a1 = pos_params(bs, ppN + 1, cbase);
            ooA = (size_t)2 * (size_t)un * C + cbase;
            ISSUE(a0, a1, dA0, dA1, dA2, dA3, dA4, dA5, dA6, dA7);
        }
        CONSUME(b0, b1, ooB, dB0, dB1, dB2, dB3, dB4, dB5, dB6, dB7);
        ++u;
        if (!hasA) break;
    }
}

extern "C" void kernel_launch(void* const* d_in, const int* in_sizes, int n_in,
                              void* d_out, int out_size, void* d_ws, size_t ws_size,
                              hipStream_t stream) {
    const int*   image_shape = (const int*)d_in[0];
    const float* boxes       = (const float*)d_in[1];
    // d_in[2] = scores (unused by the reference output)
    const float* f0 = (const float*)d_in[3];
    const float* f1 = (const float*)d_in[4];
    const float* f2 = (const float*)d_in[5];
    const float* f3 = (const float*)d_in[6];
    const float* f4 = (const float*)d_in[7];
    float* out = (float*)d_out;

    const int N = in_sizes[1] / 4;      // boxes: (1, N, 4)
    const int units  = N * HALF;        // position pairs (POS even)
    const int nwaves = NBLK * 4;

    roi_align_persist<<<NBLK, 256, 0, stream>>>(
        image_shape, boxes, f0, f1, f2, f3, f4, out, units, nwaves);
}

// Round 8
// 51.964 us; speedup vs baseline: 1.1466x; 1.1466x over previous
//
#include <hip/hip_runtime.h>

// RoiAlign on FPN pyramid.  Output: (1, N, 14, 14, 256) fp32.  N = 512.
// R7 = revert to R5 (best measured: 52.3 us). Single mono kernel, PPW=2,
//     XCD-aware bijective box-chunk swizzle, cache-bypass stores.
// Evidence across R0..R6: effective EA traffic rate pinned at ~3.96 TB/s
// regardless of occupancy (27-73%), VALUBusy (12-48%), MLP depth, store
// policy, or persistent scheduling. FETCH ~107 MB ~ unique pyramid union;
// WRITE = 100 MB compulsory. This kernel sits at the gather-mix service wall.

#define CROP 14
#define POS (CROP * CROP)        // 196
#define C 256
#define CANON 224.0f
#define EPSF 1e-7f

typedef float vfloat4 __attribute__((ext_vector_type(4)));

__device__ __forceinline__ void store_bypass(float* p, vfloat4 v) {
    asm volatile("global_store_dwordx4 %0, %1, off sc0 sc1 nt"
                 :
                 : "v"(p), "v"(v)
                 : "memory");
}

__global__ __launch_bounds__(256) void roi_align_kernel(
    const int* __restrict__ image_shape,
    const float* __restrict__ boxes,
    const float* __restrict__ f0,
    const float* __restrict__ f1,
    const float* __restrict__ f2,
    const float* __restrict__ f3,
    const float* __restrict__ f4,
    float* __restrict__ out)
{
    // bijective XCD swizzle: consecutive logical blocks (same box) -> one XCD.
    const int nwg = gridDim.x;
    const int q = nwg >> 3, r = nwg & 7;
    const int xcd = blockIdx.x & 7, slot = blockIdx.x >> 3;
    const int blk = (xcd < r ? xcd * (q + 1) : r * (q + 1) + (xcd - r) * q) + slot;

    const int box      = blk / 25;
    const int blkInBox = blk % 25;
    const int wave = threadIdx.x >> 6;
    const int lane = threadIdx.x & 63;
    const int p0 = blkInBox * 8 + wave * 2;

    const float imgh = (float)image_shape[1];
    const float imgw = (float)image_shape[2];
    const float bx1 = boxes[box * 4 + 0];
    const float by1 = boxes[box * 4 + 1];
    const float bx2 = boxes[box * 4 + 2];
    const float by2 = boxes[box * 4 + 3];

    // level selection (reference semantics)
    const float w  = bx2 - bx1;
    const float h  = by2 - by1;
    const float sz = sqrtf(w * h);
    float lvf = floorf(1.0f + log2f(sz / CANON + EPSF));
    lvf = fminf(fmaxf(lvf, 0.0f), 4.0f);
    const int lv = (int)lvf;

    const int   s  = 256 >> lv;
    const float fh = (float)s;
    const float fw = (float)s;

    const float ny1 = by1 / imgh * fh / (fh - 1.0f);
    const float nx1 = bx1 / imgw * fw / (fw - 1.0f);
    const float ny2 = (by2 / imgh * fh - 1.0f) / (fh - 1.0f);
    const float nx2 = (bx2 / imgw * fw - 1.0f) / (fw - 1.0f);

    const float* __restrict__ f =
        (lv == 0) ? f0 : (lv == 1) ? f1 : (lv == 2) ? f2 : (lv == 3) ? f3 : f4;
    const int cbase = lane * 4;

    #pragma unroll
    for (int k = 0; k < 2; ++k) {
        const int p = p0 + k;
        if (p >= POS) continue;
        const int py = p / CROP;
        const int px = p % CROP;
        const float ty = (float)py / (float)(CROP - 1);
        const float tx = (float)px / (float)(CROP - 1);
        const float yc = (ny1 * (1.0f - ty) + ny2 * ty) * (fh - 1.0f);
        const float xc = (nx1 * (1.0f - tx) + nx2 * tx) * (fw - 1.0f);

        const float ylo = floorf(yc);
        const float fy  = yc - ylo;
        const int y0  = (int)fminf(fmaxf(ylo,        0.0f), fh - 1.0f);
        const int y1i = (int)fminf(fmaxf(ylo + 1.0f, 0.0f), fh - 1.0f);
        const bool vy = (yc >= 0.0f) && (yc <= fh - 1.0f);

        const float xlo = floorf(xc);
        const float fx  = xc - xlo;
        const int x0  = (int)fminf(fmaxf(xlo,        0.0f), fw - 1.0f);
        const int x1i = (int)fminf(fmaxf(xlo + 1.0f, 0.0f), fw - 1.0f);
        const bool vx = (xc >= 0.0f) && (xc <= fw - 1.0f);

        vfloat4 o;
        if (vy && vx) {
            const vfloat4 tl = *(const vfloat4*)(f + ((size_t)y0  * s + x0 ) * C + cbase);
            const vfloat4 tr = *(const vfloat4*)(f + ((size_t)y0  * s + x1i) * C + cbase);
            const vfloat4 bl = *(const vfloat4*)(f + ((size_t)y1i * s + x0 ) * C + cbase);
            const vfloat4 br = *(const vfloat4*)(f + ((size_t)y1i * s + x1i) * C + cbase);
            const vfloat4 top = tl + (tr - tl) * fx;
            const vfloat4 bot = bl + (br - bl) * fx;
            o = top + (bot - top) * fy;
        } else { o = (vfloat4)0.0f; }

        store_bypass(out + ((size_t)box * POS + p) * C + cbase, o);
    }
}

extern "C" void kernel_launch(void* const* d_in, const int* in_sizes, int n_in,
                              void* d_out, int out_size, void* d_ws, size_t ws_size,
                              hipStream_t stream) {
    const int*   image_shape = (const int*)d_in[0];
    const float* boxes       = (const float*)d_in[1];
    // d_in[2] = scores (unused by the reference output)
    const float* f0 = (const float*)d_in[3];
    const float* f1 = (const float*)d_in[4];
    const float* f2 = (const float*)d_in[5];
    const float* f3 = (const float*)d_in[6];
    const float* f4 = (const float*)d_in[7];
    float* out = (float*)d_out;

    const int N = in_sizes[1] / 4;  // boxes: (1, N, 4)

    roi_align_kernel<<<N * 25, 256, 0, stream>>>(
        image_shape, boxes, f0, f1, f2, f3, f4, out);
}